// Round 1
// baseline (596.786 us; speedup 1.0000x reference)
//
#include <hip/hip_runtime.h>
#include <hip/hip_bf16.h>
#include <stdint.h>

#define N_EXPERTS 8
#define DIM 2048
#define INTER 1408
#define NGU (2*INTER)          // 2816
#define TOK_E 2048             // tokens per expert
#define TOTAL_TOKENS 16384

typedef __attribute__((ext_vector_type(8))) short short8;
typedef __attribute__((ext_vector_type(4))) float f32x4;

__device__ __forceinline__ unsigned short f2bf(float f) {
    union { float f; unsigned u; } v; v.f = f;
    unsigned r = v.u + 0x7FFF + ((v.u >> 16) & 1);   // RNE
    return (unsigned short)(r >> 16);
}

#define GLOAD16(G, L) __builtin_amdgcn_global_load_lds( \
    (const __attribute__((address_space(1))) void*)(G), \
    (__attribute__((address_space(3))) void*)(L), 16, 0, 0)

// ---------------- prep kernels ----------------

__global__ void convert_x(const float* __restrict__ in, unsigned short* __restrict__ out, int n8) {
    int i = blockIdx.x * blockDim.x + threadIdx.x;
    int stride = gridDim.x * blockDim.x;
    for (; i < n8; i += stride) {
        const float4* p = (const float4*)(in + (size_t)i * 8);
        float4 v0 = p[0], v1 = p[1];
        union { unsigned short u[8]; uint4 q; } o;
        o.u[0]=f2bf(v0.x); o.u[1]=f2bf(v0.y); o.u[2]=f2bf(v0.z); o.u[3]=f2bf(v0.w);
        o.u[4]=f2bf(v1.x); o.u[5]=f2bf(v1.y); o.u[6]=f2bf(v1.z); o.u[7]=f2bf(v1.w);
        *(uint4*)(out + (size_t)i * 8) = o.q;
    }
}

// in: [E][K][N] fp32 -> out: [E][N][K] bf16 (rows optionally permuted for geglu grouping)
__global__ void transpose_convert(const float* __restrict__ in, unsigned short* __restrict__ out,
                                  int K, int N, int permute) {
    __shared__ float tile[32][33];
    int tx = threadIdx.x & 31, ty = threadIdx.x >> 5;   // 32 x 8
    int n0 = blockIdx.x * 32, k0 = blockIdx.y * 32;
    size_t ein  = (size_t)blockIdx.z * K * N;
    size_t eout = (size_t)blockIdx.z * N * K;
    #pragma unroll
    for (int r = ty; r < 32; r += 8)
        tile[r][tx] = in[ein + (size_t)(k0 + r) * N + n0 + tx];
    __syncthreads();
    #pragma unroll
    for (int r = ty; r < 32; r += 8) {
        int c = n0 + r;           // original column
        int dr = c;
        if (permute) {            // geglu grouping: B' row = 64*(a>>5) + (a&31) + 32*(c&1), a=c>>1
            int a = c >> 1;
            dr = ((a >> 5) << 6) + (a & 31) + ((c & 1) << 5);
        }
        out[eout + (size_t)dr * K + k0 + tx] = f2bf(tile[tx][r]);
    }
}

// ---------------- GEMM 1: x @ gate_up^T (permuted) + GEGLU, act out (bf16) ----------------

__global__ __launch_bounds__(256)
void gemm_gu(const unsigned short* __restrict__ A,    // x bf16 [16384][2048]
             const unsigned short* __restrict__ Bt,   // [E][2816][2048] permuted-transposed
             const float* __restrict__ probs,         // [16384]
             unsigned short* __restrict__ act) {      // [16384][1408] bf16
    __shared__ unsigned short sA[128 * 32];
    __shared__ unsigned short sB[128 * 32];
    const int t = threadIdx.x;
    const int lane = t & 63, wid = t >> 6;
    const int wm = wid >> 1, wn = wid & 1;
    const int e = blockIdx.z, tm = blockIdx.y, tn = blockIdx.x;
    const int srow = t >> 2;         // staging row within 64-row chunk
    const int skg  = t & 3;          // staging k-group (16B)

    const unsigned short* gA = A  + (size_t)(e * TOK_E + tm * 128) * DIM;
    const unsigned short* gB = Bt + (size_t)e * NGU * DIM + (size_t)(tn * 128) * DIM;

    f32x4 acc[4][4];
    #pragma unroll
    for (int m = 0; m < 4; ++m)
        #pragma unroll
        for (int n = 0; n < 4; ++n) acc[m][n] = (f32x4)0.0f;

    for (int k0 = 0; k0 < DIM; k0 += 32) {
        #pragma unroll
        for (int i = 0; i < 2; ++i) {
            GLOAD16(gA + (size_t)(i * 64 + srow) * DIM + k0 + skg * 8, sA + (i * 256 + wid * 64) * 8);
            GLOAD16(gB + (size_t)(i * 64 + srow) * DIM + k0 + skg * 8, sB + (i * 256 + wid * 64) * 8);
        }
        __syncthreads();
        short8 af[4], bfr[4];
        #pragma unroll
        for (int m = 0; m < 4; ++m)
            af[m] = *(const short8*)&sA[(wm * 64 + m * 16 + (lane & 15)) * 32 + (lane >> 4) * 8];
        #pragma unroll
        for (int n = 0; n < 4; ++n)
            bfr[n] = *(const short8*)&sB[(wn * 64 + n * 16 + (lane & 15)) * 32 + (lane >> 4) * 8];
        #pragma unroll
        for (int m = 0; m < 4; ++m)
            #pragma unroll
            for (int n = 0; n < 4; ++n)
                acc[m][n] = __builtin_amdgcn_mfma_f32_16x16x32_bf16(af[m], bfr[n], acc[m][n], 0, 0, 0);
        __syncthreads();
    }

    const int col = lane & 15, rgrp = lane >> 4;
    #pragma unroll
    for (int m = 0; m < 4; ++m) {
        #pragma unroll
        for (int j = 0; j < 4; ++j) {
            int row = e * TOK_E + tm * 128 + wm * 64 + m * 16 + rgrp * 4 + j;
            float p = probs[row];
            #pragma unroll
            for (int n = 0; n < 2; ++n) {
                float g = acc[m][n][j];
                float u = acc[m][n + 2][j];
                g = fminf(g, 7.0f);
                u = fminf(fmaxf(u, -7.0f), 7.0f);
                float glu = g / (1.0f + __expf(-1.702f * g));
                float r = glu * (u + 1.0f) * p;
                int acol = tn * 64 + wn * 32 + n * 16 + col;
                act[(size_t)row * INTER + acol] = f2bf(r);
            }
        }
    }
}

// ---------------- GEMM 2: act @ down^T, fp32 out ----------------

__global__ __launch_bounds__(256)
void gemm_down(const unsigned short* __restrict__ A,   // act bf16 [16384][1408]
               const unsigned short* __restrict__ Bt,  // [E][2048][1408]
               float* __restrict__ out) {               // [16384][2048] fp32
    __shared__ unsigned short sA[128 * 32];
    __shared__ unsigned short sB[128 * 32];
    const int t = threadIdx.x;
    const int lane = t & 63, wid = t >> 6;
    const int wm = wid >> 1, wn = wid & 1;
    const int e = blockIdx.z, tm = blockIdx.y, tn = blockIdx.x;
    const int srow = t >> 2;
    const int skg  = t & 3;

    const unsigned short* gA = A  + (size_t)(e * TOK_E + tm * 128) * INTER;
    const unsigned short* gB = Bt + (size_t)e * DIM * INTER + (size_t)(tn * 128) * INTER;

    f32x4 acc[4][4];
    #pragma unroll
    for (int m = 0; m < 4; ++m)
        #pragma unroll
        for (int n = 0; n < 4; ++n) acc[m][n] = (f32x4)0.0f;

    for (int k0 = 0; k0 < INTER; k0 += 32) {
        #pragma unroll
        for (int i = 0; i < 2; ++i) {
            GLOAD16(gA + (size_t)(i * 64 + srow) * INTER + k0 + skg * 8, sA + (i * 256 + wid * 64) * 8);
            GLOAD16(gB + (size_t)(i * 64 + srow) * INTER + k0 + skg * 8, sB + (i * 256 + wid * 64) * 8);
        }
        __syncthreads();
        short8 af[4], bfr[4];
        #pragma unroll
        for (int m = 0; m < 4; ++m)
            af[m] = *(const short8*)&sA[(wm * 64 + m * 16 + (lane & 15)) * 32 + (lane >> 4) * 8];
        #pragma unroll
        for (int n = 0; n < 4; ++n)
            bfr[n] = *(const short8*)&sB[(wn * 64 + n * 16 + (lane & 15)) * 32 + (lane >> 4) * 8];
        #pragma unroll
        for (int m = 0; m < 4; ++m)
            #pragma unroll
            for (int n = 0; n < 4; ++n)
                acc[m][n] = __builtin_amdgcn_mfma_f32_16x16x32_bf16(af[m], bfr[n], acc[m][n], 0, 0, 0);
        __syncthreads();
    }

    const int col = lane & 15, rgrp = lane >> 4;
    #pragma unroll
    for (int m = 0; m < 4; ++m) {
        #pragma unroll
        for (int j = 0; j < 4; ++j) {
            int row = e * TOK_E + tm * 128 + wm * 64 + m * 16 + rgrp * 4 + j;
            #pragma unroll
            for (int n = 0; n < 4; ++n) {
                int cn = tn * 128 + wn * 64 + n * 16 + col;
                out[(size_t)row * DIM + cn] = acc[m][n][j];
            }
        }
    }
}

// ---------------- launcher ----------------

extern "C" void kernel_launch(void* const* d_in, const int* in_sizes, int n_in,
                              void* d_out, int out_size, void* d_ws, size_t ws_size,
                              hipStream_t stream) {
    const float* x     = (const float*)d_in[0];
    const float* probs = (const float*)d_in[1];
    const float* gup   = (const float*)d_in[2];
    const float* dwn   = (const float*)d_in[3];
    float* out = (float*)d_out;

    char* ws = (char*)d_ws;
    const size_t SZ_XB  = (size_t)TOTAL_TOKENS * DIM * 2;      // 67,108,864
    const size_t SZ_GUB = (size_t)N_EXPERTS * NGU * DIM * 2;   // 92,274,688
    const size_t SZ_DWB = (size_t)N_EXPERTS * DIM * INTER * 2; // 46,137,344
    unsigned short* xb   = (unsigned short*)(ws);
    unsigned short* gub  = (unsigned short*)(ws + SZ_XB);
    unsigned short* dwb  = (unsigned short*)(ws + SZ_XB + SZ_GUB);
    unsigned short* actb = (unsigned short*)(ws + SZ_XB + SZ_GUB + SZ_DWB);

    convert_x<<<2048, 256, 0, stream>>>(x, xb, TOTAL_TOKENS * DIM / 8);

    dim3 tg1(NGU / 32, DIM / 32, N_EXPERTS);      // (88, 64, 8)
    transpose_convert<<<tg1, 256, 0, stream>>>(gup, gub, DIM, NGU, 1);
    dim3 tg2(DIM / 32, INTER / 32, N_EXPERTS);    // (64, 44, 8)
    transpose_convert<<<tg2, 256, 0, stream>>>(dwn, dwb, INTER, DIM, 0);

    dim3 g1(NGU / 128, TOK_E / 128, N_EXPERTS);   // (22, 16, 8)
    gemm_gu<<<g1, 256, 0, stream>>>(xb, gub, probs, actb);

    dim3 g2(DIM / 128, TOK_E / 128, N_EXPERTS);   // (16, 16, 8)
    gemm_down<<<g2, 256, 0, stream>>>(actb, dwb, out);
}

// Round 2
// 564.019 us; speedup vs baseline: 1.0581x; 1.0581x over previous
//
#include <hip/hip_runtime.h>
#include <hip/hip_bf16.h>
#include <stdint.h>

#define N_EXPERTS 8
#define DIM 2048
#define INTER 1408
#define NGU (2*INTER)          // 2816
#define TOK_E 2048             // tokens per expert
#define TOTAL_TOKENS 16384
#define BK 32

typedef __attribute__((ext_vector_type(8))) short short8;
typedef __attribute__((ext_vector_type(4))) float f32x4;

__device__ __forceinline__ unsigned short f2bf(float f) {
    union { float f; unsigned u; } v; v.f = f;
    unsigned r = v.u + 0x7FFF + ((v.u >> 16) & 1);   // RNE
    return (unsigned short)(r >> 16);
}

#define GLOAD16(G, L) __builtin_amdgcn_global_load_lds( \
    (const __attribute__((address_space(1))) void*)(G), \
    (__attribute__((address_space(3))) void*)(L), 16, 0, 0)

// ---------------- prep kernels (unchanged, verified R1) ----------------

__global__ void convert_x(const float* __restrict__ in, unsigned short* __restrict__ out, int n8) {
    int i = blockIdx.x * blockDim.x + threadIdx.x;
    int stride = gridDim.x * blockDim.x;
    for (; i < n8; i += stride) {
        const float4* p = (const float4*)(in + (size_t)i * 8);
        float4 v0 = p[0], v1 = p[1];
        union { unsigned short u[8]; uint4 q; } o;
        o.u[0]=f2bf(v0.x); o.u[1]=f2bf(v0.y); o.u[2]=f2bf(v0.z); o.u[3]=f2bf(v0.w);
        o.u[4]=f2bf(v1.x); o.u[5]=f2bf(v1.y); o.u[6]=f2bf(v1.z); o.u[7]=f2bf(v1.w);
        *(uint4*)(out + (size_t)i * 8) = o.q;
    }
}

// in: [E][K][N] fp32 -> out: [E][N][K] bf16 (rows optionally permuted for geglu grouping)
__global__ void transpose_convert(const float* __restrict__ in, unsigned short* __restrict__ out,
                                  int K, int N, int permute) {
    __shared__ float tile[32][33];
    int tx = threadIdx.x & 31, ty = threadIdx.x >> 5;   // 32 x 8
    int n0 = blockIdx.x * 32, k0 = blockIdx.y * 32;
    size_t ein  = (size_t)blockIdx.z * K * N;
    size_t eout = (size_t)blockIdx.z * N * K;
    #pragma unroll
    for (int r = ty; r < 32; r += 8)
        tile[r][tx] = in[ein + (size_t)(k0 + r) * N + n0 + tx];
    __syncthreads();
    #pragma unroll
    for (int r = ty; r < 32; r += 8) {
        int c = n0 + r;           // original column
        int dr = c;
        if (permute) {            // geglu grouping: B' row = 64*(a>>5) + (a&31) + 32*(c&1), a=c>>1
            int a = c >> 1;
            dr = ((a >> 5) << 6) + (a & 31) + ((c & 1) << 5);
        }
        out[eout + (size_t)dr * K + k0 + tx] = f2bf(tile[tx][r]);
    }
}

// ---------------- 256x256xBK32 pipelined GEMM machinery ----------------
// LDS: sA/sB each 4 buffers x (256 rows x 32 cols) bf16 = 64 KB each, 128 KB total.
// Storage swizzle (involution): phys_byte = log_byte ^ (((log_byte>>7)&7)<<4)
//   i.e. 16B-slot index (3 bits) XOR row-pair index (low 3 bits).
// global_load_lds writes LINEAR dest; the global SOURCE address is pre-swizzled;
// ds_read applies the same XOR. (rule 21: both-sides-or-neither)

#define GEMM_PROLOG(LDK_) \
    const int t = threadIdx.x; \
    const int lane = t & 63, wid = t >> 6; \
    const int wm = wid >> 2, wn = wid & 3;            /* 2 x 4 wave grid */ \
    const int l15 = lane & 15; \
    const int sl3 = (t & 7) ^ ((t >> 3) & 7); \
    const int srow = ((t >> 3) << 1) + (sl3 >> 2);    /* 0..127 */ \
    const int scol = (sl3 & 3) * 8; \
    const size_t offA0 = (size_t)srow * (LDK_) + scol; \
    const size_t offA1 = (size_t)(128 + srow) * (LDK_) + scol; \
    const int effSlot = ((lane >> 4) | ((l15 & 1) << 2)) ^ ((l15 >> 1) & 7); \
    const int rdO2 = (l15 >> 1) * 64 + effSlot * 8;   /* shorts within tile */

#define STAGE(kt_, b_) do { \
    const unsigned short* ga_ = gA + (size_t)(kt_) * BK; \
    const unsigned short* gb_ = gB + (size_t)(kt_) * BK; \
    unsigned short* la_ = &sA[(b_) * 8192 + wid * 512]; \
    unsigned short* lb_ = &sB[(b_) * 8192 + wid * 512]; \
    GLOAD16(ga_ + offA0, la_); \
    GLOAD16(ga_ + offA1, la_ + 4096); \
    GLOAD16(gb_ + offA0, lb_); \
    GLOAD16(gb_ + offA1, lb_ + 4096); \
} while (0)

#define COMPUTE_TILE(b_) do { \
    const unsigned short* pA_ = &sA[(b_) * 8192 + wm * 4096 + rdO2]; \
    const unsigned short* pB_ = &sB[(b_) * 8192 + wn * 2048 + rdO2]; \
    short8 af[8], bfx[4]; \
    _Pragma("unroll") for (int m_ = 0; m_ < 8; ++m_) af[m_] = *(const short8*)(pA_ + m_ * 512); \
    _Pragma("unroll") for (int n_ = 0; n_ < 4; ++n_) bfx[n_] = *(const short8*)(pB_ + n_ * 512); \
    __builtin_amdgcn_s_setprio(1); \
    _Pragma("unroll") for (int m_ = 0; m_ < 8; ++m_) \
        _Pragma("unroll") for (int n_ = 0; n_ < 4; ++n_) \
            acc[m_][n_] = __builtin_amdgcn_mfma_f32_16x16x32_bf16(af[m_], bfx[n_], acc[m_][n_], 0, 0, 0); \
    __builtin_amdgcn_s_setprio(0); \
} while (0)

#define BOUNDARY(N_) do { \
    asm volatile("s_waitcnt vmcnt(" #N_ ")" ::: "memory"); \
    __builtin_amdgcn_s_barrier(); \
} while (0)

#define GEMM_BODY(NT_) \
    f32x4 acc[8][4]; \
    _Pragma("unroll") for (int m_ = 0; m_ < 8; ++m_) \
        _Pragma("unroll") for (int n_ = 0; n_ < 4; ++n_) acc[m_][n_] = (f32x4)0.0f; \
    STAGE(0, 0); STAGE(1, 1); STAGE(2, 2); \
    for (int kt = 0; kt < (NT_) - 3; ++kt) { \
        BOUNDARY(8); \
        STAGE(kt + 3, (kt + 3) & 3); \
        COMPUTE_TILE(kt & 3); \
    } \
    BOUNDARY(8); COMPUTE_TILE(((NT_) - 3) & 3); \
    BOUNDARY(4); COMPUTE_TILE(((NT_) - 2) & 3); \
    BOUNDARY(0); COMPUTE_TILE(((NT_) - 1) & 3);

// ---------------- GEMM 1: x @ gate_up^T (permuted) + GEGLU, bf16 act out ----------------

__global__ __launch_bounds__(512, 2)
void gemm_gu(const unsigned short* __restrict__ A,    // x bf16 [16384][2048]
             const unsigned short* __restrict__ Bt,   // [E][2816][2048] permuted-transposed
             const float* __restrict__ probs,         // [16384]
             unsigned short* __restrict__ act) {      // [16384][1408] bf16
    __shared__ unsigned short sA[4 * 8192];
    __shared__ unsigned short sB[4 * 8192];
    GEMM_PROLOG(DIM)
    const int bid = blockIdx.x;           // 704 = 8 experts * (8 tm * 11 tn)
    const int e = bid & 7;                // expert per XCD (T1)
    const int local = bid >> 3;           // [0, 88), tm-fastest
    const int tm = local & 7;
    const int tn = local >> 3;            // [0, 11)
    const unsigned short* gA = A  + (size_t)(e * TOK_E + tm * 256) * DIM;
    const unsigned short* gB = Bt + (size_t)e * NGU * DIM + (size_t)(tn * 256) * DIM;

    GEMM_BODY(64)   // K = 2048 = 64 * 32

    const int col = l15, rgrp = lane >> 4;
    #pragma unroll
    for (int m = 0; m < 8; ++m) {
        const int row0 = e * TOK_E + tm * 256 + wm * 128 + m * 16 + rgrp * 4;
        #pragma unroll
        for (int j = 0; j < 4; ++j) {
            float p = probs[row0 + j];
            #pragma unroll
            for (int n = 0; n < 2; ++n) {
                float g = fminf(acc[m][n][j], 7.0f);
                float u = fminf(fmaxf(acc[m][n + 2][j], -7.0f), 7.0f);
                float glu = g / (1.0f + __expf(-1.702f * g));
                float r = glu * (u + 1.0f) * p;
                act[(size_t)(row0 + j) * INTER + tn * 128 + wn * 32 + n * 16 + col] = f2bf(r);
            }
        }
    }
}

// ---------------- GEMM 2: act @ down^T, fp32 out ----------------

__global__ __launch_bounds__(512, 2)
void gemm_down(const unsigned short* __restrict__ A,   // act bf16 [16384][1408]
               const unsigned short* __restrict__ Bt,  // [E][2048][1408]
               float* __restrict__ out) {               // [16384][2048] fp32
    __shared__ unsigned short sA[4 * 8192];
    __shared__ unsigned short sB[4 * 8192];
    GEMM_PROLOG(INTER)
    const int bid = blockIdx.x;           // 512 = 8 experts * (8 tm * 8 tn)
    const int e = bid & 7;
    const int local = bid >> 3;           // [0, 64), tm-fastest
    const int tm = local & 7;
    const int tn = local >> 3;            // [0, 8)
    const unsigned short* gA = A  + (size_t)(e * TOK_E + tm * 256) * INTER;
    const unsigned short* gB = Bt + (size_t)e * DIM * INTER + (size_t)(tn * 256) * INTER;

    GEMM_BODY(44)   // K = 1408 = 44 * 32

    const int col = l15, rgrp = lane >> 4;
    #pragma unroll
    for (int m = 0; m < 8; ++m) {
        const int row0 = e * TOK_E + tm * 256 + wm * 128 + m * 16 + rgrp * 4;
        #pragma unroll
        for (int j = 0; j < 4; ++j) {
            #pragma unroll
            for (int n = 0; n < 4; ++n) {
                out[(size_t)(row0 + j) * DIM + tn * 256 + wn * 64 + n * 16 + col] = acc[m][n][j];
            }
        }
    }
}

// ---------------- launcher ----------------

extern "C" void kernel_launch(void* const* d_in, const int* in_sizes, int n_in,
                              void* d_out, int out_size, void* d_ws, size_t ws_size,
                              hipStream_t stream) {
    const float* x     = (const float*)d_in[0];
    const float* probs = (const float*)d_in[1];
    const float* gup   = (const float*)d_in[2];
    const float* dwn   = (const float*)d_in[3];
    float* out = (float*)d_out;

    char* ws = (char*)d_ws;
    const size_t SZ_XB  = (size_t)TOTAL_TOKENS * DIM * 2;      // 67,108,864
    const size_t SZ_GUB = (size_t)N_EXPERTS * NGU * DIM * 2;   // 92,274,688
    const size_t SZ_DWB = (size_t)N_EXPERTS * DIM * INTER * 2; // 46,137,344
    unsigned short* xb   = (unsigned short*)(ws);
    unsigned short* gub  = (unsigned short*)(ws + SZ_XB);
    unsigned short* dwb  = (unsigned short*)(ws + SZ_XB + SZ_GUB);
    unsigned short* actb = (unsigned short*)(ws + SZ_XB + SZ_GUB + SZ_DWB);

    convert_x<<<2048, 256, 0, stream>>>(x, xb, TOTAL_TOKENS * DIM / 8);

    dim3 tg1(NGU / 32, DIM / 32, N_EXPERTS);      // (88, 64, 8)
    transpose_convert<<<tg1, 256, 0, stream>>>(gup, gub, DIM, NGU, 1);
    dim3 tg2(DIM / 32, INTER / 32, N_EXPERTS);    // (64, 44, 8)
    transpose_convert<<<tg2, 256, 0, stream>>>(dwn, dwb, INTER, DIM, 0);

    gemm_gu<<<704, 512, 0, stream>>>(xb, gub, probs, actb);
    gemm_down<<<512, 512, 0, stream>>>(actb, dwb, out);
}